// Round 1
// baseline (241.872 us; speedup 1.0000x reference)
//
#include <hip/hip_runtime.h>

#define N_ATOMS 262144
#define NGRAPH  2048
#define INV_SCALE 0.17677669529663687f  // 1/sqrt(32)

// ---------------- K1: P[h][i] = sum_d Wk[i][h*32+d]*q[h][d];  c[h] = bk_h . q_h
__global__ void k_prep(const float* __restrict__ Wk, const float* __restrict__ bk,
                       const float* __restrict__ q, float* __restrict__ P,
                       float* __restrict__ c) {
  int h = blockIdx.x, i = threadIdx.x;
  float s = 0.f;
  #pragma unroll
  for (int d = 0; d < 32; ++d)
    s = fmaf(Wk[i * 256 + h * 32 + d], q[h * 32 + d], s);
  P[h * 256 + i] = s;
  if (i == 0) {
    float cc = 0.f;
    #pragma unroll
    for (int d = 0; d < 32; ++d) cc = fmaf(bk[h * 32 + d], q[h * 32 + d], cc);
    c[h] = cc;
  }
}

// ---------------- K2: scores[n][h] = (x[n].P[h] + c[h]) / SCALE
// one wave per atom; lane l holds features 4l..4l+3 of x and P.
__global__ __launch_bounds__(256) void k_scores(const float* __restrict__ x,
                                                const float* __restrict__ P,
                                                const float* __restrict__ c,
                                                float* __restrict__ scores) {
  int lane = threadIdx.x & 63;
  int wid = (blockIdx.x << 2) | (threadIdx.x >> 6);
  float4 Pl[8];
  #pragma unroll
  for (int h = 0; h < 8; ++h)
    Pl[h] = *reinterpret_cast<const float4*>(P + h * 256 + 4 * lane);
  float cl = c[lane & 7];
  for (int n = wid; n < N_ATOMS; n += 8192) {
    float4 xv = *reinterpret_cast<const float4*>(x + (size_t)n * 256 + 4 * lane);
    float acc[8];
    #pragma unroll
    for (int h = 0; h < 8; ++h)
      acc[h] = fmaf(xv.x, Pl[h].x,
               fmaf(xv.y, Pl[h].y, fmaf(xv.z, Pl[h].z, xv.w * Pl[h].w)));
    #pragma unroll
    for (int off = 1; off < 64; off <<= 1) {
      #pragma unroll
      for (int h = 0; h < 8; ++h) acc[h] += __shfl_xor(acc[h], off, 64);
    }
    if (lane < 8) {
      float v = acc[0];
      #pragma unroll
      for (int h = 1; h < 8; ++h) v = (lane == h) ? acc[h] : v;
      scores[(size_t)n * 8 + lane] = (v + cl) * INV_SCALE;
    }
  }
}

// ---------------- K3: per-graph segment softmax, normalize w in place.
// batch is sorted; one 64-thread block per graph; binary-search bounds.
__global__ __launch_bounds__(64) void k_stats(const int* __restrict__ batch,
                                              float* __restrict__ w,
                                              int* __restrict__ bounds) {
  int b = blockIdx.x;
  __shared__ int sse[2];
  if (threadIdx.x < 2) {
    int target = b + threadIdx.x;
    int lo = 0, hi = N_ATOMS;
    while (lo < hi) {
      int mid = (lo + hi) >> 1;
      if (batch[mid] < target) lo = mid + 1; else hi = mid;
    }
    sse[threadIdx.x] = lo;
  }
  __syncthreads();
  int s = sse[0], e = sse[1];
  int t = threadIdx.x, h = t & 7, ar = t >> 3;
  float mx = -1e30f;
  for (int n = s + ar; n < e; n += 8) mx = fmaxf(mx, w[(size_t)n * 8 + h]);
  #pragma unroll
  for (int off = 8; off < 64; off <<= 1) mx = fmaxf(mx, __shfl_xor(mx, off, 64));
  float sm = 0.f;
  for (int n = s + ar; n < e; n += 8) sm += __expf(w[(size_t)n * 8 + h] - mx);
  #pragma unroll
  for (int off = 8; off < 64; off <<= 1) sm += __shfl_xor(sm, off, 64);
  float inv = (e > s) ? 1.0f / sm : 0.0f;
  for (int n = s + ar; n < e; n += 8) {
    size_t idx = (size_t)n * 8 + h;
    w[idx] = __expf(w[idx] - mx) * inv;
  }
  if (t == 0) { bounds[2 * b] = s; bounds[2 * b + 1] = e; }
}

__device__ inline void fma4(float4& a, float s, const float4& v) {
  a.x = fmaf(s, v.x, a.x); a.y = fmaf(s, v.y, a.y);
  a.z = fmaf(s, v.z, a.z); a.w = fmaf(s, v.w, a.w);
}

// ---------------- K4: A[b][h][i] = sum_{n in seg b} w[n][h] * x[n][i]
// block per graph, 4 waves; wave handles atoms a%4; lane l = features 4l..4l+3.
__global__ __launch_bounds__(256) void k_accum(const float* __restrict__ x,
                                               const float* __restrict__ w,
                                               const int* __restrict__ bounds,
                                               float* __restrict__ Ag) {
  int b = blockIdx.x;
  int s = bounds[2 * b], e = bounds[2 * b + 1];
  int t = threadIdx.x, lane = t & 63, wv = t >> 6;
  float4 A[8];
  #pragma unroll
  for (int h = 0; h < 8; ++h) A[h] = make_float4(0.f, 0.f, 0.f, 0.f);
  __shared__ float wlds[256];          // 32 atoms x 8 heads
  __shared__ float As[4][8][256];      // per-wave partial A (32 KB)

  for (int c0 = s; c0 < e; c0 += 32) {
    int cnt = min(32, e - c0);
    __syncthreads();
    if (t < cnt * 8) wlds[t] = w[(size_t)c0 * 8 + t];
    __syncthreads();
    for (int a = wv; a < cnt; a += 4) {
      int n = c0 + a;
      float4 xv = *reinterpret_cast<const float4*>(x + (size_t)n * 256 + 4 * lane);
      float w0 = wlds[a * 8 + 0], w1 = wlds[a * 8 + 1], w2 = wlds[a * 8 + 2], w3 = wlds[a * 8 + 3];
      float w4 = wlds[a * 8 + 4], w5 = wlds[a * 8 + 5], w6 = wlds[a * 8 + 6], w7 = wlds[a * 8 + 7];
      fma4(A[0], w0, xv); fma4(A[1], w1, xv); fma4(A[2], w2, xv); fma4(A[3], w3, xv);
      fma4(A[4], w4, xv); fma4(A[5], w5, xv); fma4(A[6], w6, xv); fma4(A[7], w7, xv);
    }
  }
  __syncthreads();
  #pragma unroll
  for (int h = 0; h < 8; ++h)
    *reinterpret_cast<float4*>(&As[wv][h][4 * lane]) = A[h];
  __syncthreads();
  const float* Asf = &As[0][0][0];
  #pragma unroll
  for (int r = 0; r < 8; ++r) {
    int idx = r * 256 + t;
    float v = Asf[idx] + Asf[2048 + idx] + Asf[4096 + idx] + Asf[6144 + idx];
    Ag[(size_t)b * 2048 + idx] = v;
  }
}

// ---------------- K5: att = A . Wv + bv (nonempty), out = att . Wo + bo
// block handles 4 graphs; thread t = output column.
__global__ __launch_bounds__(256) void k_out(const float* __restrict__ Ag,
                                             const int* __restrict__ bounds,
                                             const float* __restrict__ Wv,
                                             const float* __restrict__ bv,
                                             const float* __restrict__ Wo,
                                             const float* __restrict__ bo,
                                             float* __restrict__ out) {
  __shared__ float Alds[4 * 2048];   // 32 KB
  __shared__ float attlds[4 * 256];  // 4 KB
  __shared__ float eflag[4];
  int b0 = blockIdx.x * 4;
  int t = threadIdx.x;
  #pragma unroll
  for (int r = 0; r < 32; ++r) {
    int idx = r * 256 + t;
    Alds[idx] = Ag[(size_t)b0 * 2048 + idx];
  }
  if (t < 4) {
    int s = bounds[2 * (b0 + t)], e = bounds[2 * (b0 + t) + 1];
    eflag[t] = (e > s) ? 1.0f : 0.0f;
  }
  __syncthreads();
  int h = t >> 5;
  float bvk = bv[t];
  float acc[4];
  #pragma unroll
  for (int g = 0; g < 4; ++g) acc[g] = 0.f;
  for (int i4 = 0; i4 < 64; ++i4) {
    float aa[4][4];
    #pragma unroll
    for (int g = 0; g < 4; ++g) {
      float4 v = *reinterpret_cast<const float4*>(&Alds[g * 2048 + h * 256 + i4 * 4]);
      aa[g][0] = v.x; aa[g][1] = v.y; aa[g][2] = v.z; aa[g][3] = v.w;
    }
    #pragma unroll
    for (int j = 0; j < 4; ++j) {
      float wvv = Wv[(size_t)(i4 * 4 + j) * 256 + t];
      #pragma unroll
      for (int g = 0; g < 4; ++g) acc[g] = fmaf(aa[g][j], wvv, acc[g]);
    }
  }
  #pragma unroll
  for (int g = 0; g < 4; ++g) attlds[g * 256 + t] = acc[g] + bvk * eflag[g];
  __syncthreads();
  float boj = bo[t];
  float o[4];
  #pragma unroll
  for (int g = 0; g < 4; ++g) o[g] = boj;
  for (int k4 = 0; k4 < 64; ++k4) {
    float aa[4][4];
    #pragma unroll
    for (int g = 0; g < 4; ++g) {
      float4 v = *reinterpret_cast<const float4*>(&attlds[g * 256 + k4 * 4]);
      aa[g][0] = v.x; aa[g][1] = v.y; aa[g][2] = v.z; aa[g][3] = v.w;
    }
    #pragma unroll
    for (int j = 0; j < 4; ++j) {
      float wo = Wo[(size_t)(k4 * 4 + j) * 256 + t];
      #pragma unroll
      for (int g = 0; g < 4; ++g) o[g] = fmaf(aa[g][j], wo, o[g]);
    }
  }
  #pragma unroll
  for (int g = 0; g < 4; ++g) out[(size_t)(b0 + g) * 256 + t] = o[g];
}

extern "C" void kernel_launch(void* const* d_in, const int* in_sizes, int n_in,
                              void* d_out, int out_size, void* d_ws, size_t ws_size,
                              hipStream_t stream) {
  const float* x   = (const float*)d_in[0];
  const int*   bat = (const int*)d_in[1];
  const float* q   = (const float*)d_in[2];
  const float* Wk  = (const float*)d_in[3];
  const float* bk  = (const float*)d_in[4];
  const float* Wv  = (const float*)d_in[5];
  const float* bv  = (const float*)d_in[6];
  const float* Wo  = (const float*)d_in[7];
  const float* bo  = (const float*)d_in[8];
  float* out = (float*)d_out;

  float* ws = (float*)d_ws;
  float* P      = ws;                 // 2048 floats
  float* c      = ws + 2048;          // 8 floats
  int*   bounds = (int*)(ws + 4096);  // 4096 ints
  float* w      = ws + 8192;          // N*8 floats (scores -> normalized w)
  float* Ag     = ws + 8192 + (size_t)N_ATOMS * 8;  // 2048*2048 floats

  k_prep<<<8, 256, 0, stream>>>(Wk, bk, q, P, c);
  k_scores<<<2048, 256, 0, stream>>>(x, P, c, w);
  k_stats<<<NGRAPH, 64, 0, stream>>>(bat, w, bounds);
  k_accum<<<NGRAPH, 256, 0, stream>>>(x, w, bounds, Ag);
  k_out<<<NGRAPH / 4, 256, 0, stream>>>(Ag, bounds, Wv, bv, Wo, bo, out);
}

// Round 2
// 125.816 us; speedup vs baseline: 1.9224x; 1.9224x over previous
//
#include <hip/hip_runtime.h>

#define N_ATOMS 262144
#define NGRAPH  2048
#define INV_SCALE 0.17677669529663687f  // 1/sqrt(32)

// ---------------- K1: P[h][i] = sum_d Wk[i][h*32+d]*q[h][d];  c[h] = bk_h . q_h
__global__ void k_prep(const float* __restrict__ Wk, const float* __restrict__ bk,
                       const float* __restrict__ q, float* __restrict__ P,
                       float* __restrict__ c) {
  int h = blockIdx.x, i = threadIdx.x;
  float s = 0.f;
  #pragma unroll
  for (int d = 0; d < 32; ++d)
    s = fmaf(Wk[i * 256 + h * 32 + d], q[h * 32 + d], s);
  P[h * 256 + i] = s;
  if (i == 0) {
    float cc = 0.f;
    #pragma unroll
    for (int d = 0; d < 32; ++d) cc = fmaf(bk[h * 32 + d], q[h * 32 + d], cc);
    c[h] = cc;
  }
}

// ---------------- K1b: segment bounds via one binary search per graph.
__global__ void k_bounds(const int* __restrict__ batch, int* __restrict__ bounds) {
  int g = blockIdx.x * blockDim.x + threadIdx.x;
  if (g >= NGRAPH) return;
  int lo = 0, hi = N_ATOMS;
  while (lo < hi) {
    int mid = (lo + hi) >> 1;
    if (batch[mid] < g) lo = mid + 1; else hi = mid;
  }
  bounds[2 * g] = lo;
  if (g > 0) bounds[2 * g - 1] = lo;
  if (g == NGRAPH - 1) bounds[2 * g + 1] = N_ATOMS;
}

__device__ inline void fma4(float4& a, float s, const float4& v) {
  a.x = fmaf(s, v.x, a.x); a.y = fmaf(s, v.y, a.y);
  a.z = fmaf(s, v.z, a.z); a.w = fmaf(s, v.w, a.w);
}

// ---------------- K2: fused single-pass scores + exp + weighted accumulate.
// One block per graph, 4 waves; wave handles atoms n%4; lane l = features 4l..4l+3.
// Online (max-free) softmax: A[h] += e_h * x, d_h += e_h; normalize at end.
__global__ __launch_bounds__(256) void k_fused(const float* __restrict__ x,
                                               const float* __restrict__ P,
                                               const float* __restrict__ c,
                                               const int* __restrict__ bounds,
                                               float* __restrict__ Ag) {
  int b = blockIdx.x;
  int s = bounds[2 * b], e = bounds[2 * b + 1];
  int t = threadIdx.x, lane = t & 63, wv = t >> 6;
  // head owned by this lane's octet: h = 4*bit3 + 2*bit4 + bit5 of lane
  int h = ((lane >> 1) & 4) | ((lane >> 3) & 2) | ((lane >> 5) & 1);

  float4 Pl[8];
  #pragma unroll
  for (int k = 0; k < 8; ++k)
    Pl[k] = *reinterpret_cast<const float4*>(P + k * 256 + 4 * lane);
  float cl = c[h];

  float4 A[8];
  #pragma unroll
  for (int k = 0; k < 8; ++k) A[k] = make_float4(0.f, 0.f, 0.f, 0.f);
  float dacc = 0.f;

  for (int n = s + wv; n < e; n += 4) {
    float4 xv = *reinterpret_cast<const float4*>(x + (size_t)n * 256 + 4 * lane);
    float acc[8];
    #pragma unroll
    for (int k = 0; k < 8; ++k)
      acc[k] = fmaf(xv.x, Pl[k].x,
               fmaf(xv.y, Pl[k].y, fmaf(xv.z, Pl[k].z, xv.w * Pl[k].w)));
    // transpose-reduce: 8 head-partials/lane over 64 lanes -> 1 head total/lane
    {
      int m = lane & 8;
      float nw[4];
      #pragma unroll
      for (int j = 0; j < 4; ++j) {
        float snd = m ? acc[j] : acc[j + 4];
        float rcv = __shfl_xor(snd, 8, 64);
        nw[j] = (m ? acc[j + 4] : acc[j]) + rcv;
      }
      #pragma unroll
      for (int j = 0; j < 4; ++j) acc[j] = nw[j];
    }
    {
      int m = lane & 16;
      float nw[2];
      #pragma unroll
      for (int j = 0; j < 2; ++j) {
        float snd = m ? acc[j] : acc[j + 2];
        float rcv = __shfl_xor(snd, 16, 64);
        nw[j] = (m ? acc[j + 2] : acc[j]) + rcv;
      }
      acc[0] = nw[0]; acc[1] = nw[1];
    }
    float r;
    {
      int m = lane & 32;
      float snd = m ? acc[0] : acc[1];
      float rcv = __shfl_xor(snd, 32, 64);
      r = (m ? acc[1] : acc[0]) + rcv;
    }
    r += __shfl_xor(r, 1, 64);
    r += __shfl_xor(r, 2, 64);
    r += __shfl_xor(r, 4, 64);
    // r = full dot for head h; score -> weight
    float ev = __expf((r + cl) * INV_SCALE);
    dacc += ev;
    // broadcast: gather e for all 8 heads into head-indexed e8[]
    float o = __shfl_xor(ev, 32, 64);                 // head h^1
    float p0 = (h & 1) ? o : ev;                      // head (h&~1)
    float p1 = (h & 1) ? ev : o;                      // head (h&~1)|1
    float q0 = __shfl_xor(p0, 16, 64);                // heads ((h^2)&~1)|j
    float q1 = __shfl_xor(p1, 16, 64);
    float f0, f1, f2, f3;
    if (h & 2) { f0 = q0; f1 = q1; f2 = p0; f3 = p1; }
    else       { f0 = p0; f1 = p1; f2 = q0; f3 = q1; }
    float g0 = __shfl_xor(f0, 8, 64);                 // heads ((h^4)&~3)|j
    float g1 = __shfl_xor(f1, 8, 64);
    float g2 = __shfl_xor(f2, 8, 64);
    float g3 = __shfl_xor(f3, 8, 64);
    float e8[8];
    if (h & 4) { e8[0]=g0; e8[1]=g1; e8[2]=g2; e8[3]=g3; e8[4]=f0; e8[5]=f1; e8[6]=f2; e8[7]=f3; }
    else       { e8[0]=f0; e8[1]=f1; e8[2]=f2; e8[3]=f3; e8[4]=g0; e8[5]=g1; e8[6]=g2; e8[7]=g3; }
    #pragma unroll
    for (int k = 0; k < 8; ++k) fma4(A[k], e8[k], xv);
  }

  // epilogue: cross-wave reduce + normalize
  __shared__ float As[4][8][256];  // 32 KB
  __shared__ float dws[4][8];
  __shared__ float dinvs[8];
  #pragma unroll
  for (int k = 0; k < 8; ++k)
    *reinterpret_cast<float4*>(&As[wv][k][4 * lane]) = A[k];
  if ((lane & 7) == 0) dws[wv][h] = dacc;
  __syncthreads();
  if (t < 8) {
    float ds = dws[0][t] + dws[1][t] + dws[2][t] + dws[3][t];
    dinvs[t] = ds > 0.f ? 1.0f / ds : 0.f;
  }
  __syncthreads();
  #pragma unroll
  for (int r2 = 0; r2 < 8; ++r2) {
    float v = As[0][r2][t] + As[1][r2][t] + As[2][r2][t] + As[3][r2][t];
    Ag[(size_t)b * 2048 + r2 * 256 + t] = v * dinvs[r2];
  }
}

// ---------------- K5: att = A . Wv + bv (nonempty), out = att . Wo + bo
// block handles 4 graphs; thread t = output column.
__global__ __launch_bounds__(256) void k_out(const float* __restrict__ Ag,
                                             const int* __restrict__ bounds,
                                             const float* __restrict__ Wv,
                                             const float* __restrict__ bv,
                                             const float* __restrict__ Wo,
                                             const float* __restrict__ bo,
                                             float* __restrict__ out) {
  __shared__ float Alds[4 * 2048];   // 32 KB
  __shared__ float attlds[4 * 256];  // 4 KB
  __shared__ float eflag[4];
  int b0 = blockIdx.x * 4;
  int t = threadIdx.x;
  #pragma unroll
  for (int r = 0; r < 32; ++r) {
    int idx = r * 256 + t;
    Alds[idx] = Ag[(size_t)b0 * 2048 + idx];
  }
  if (t < 4) {
    int s = bounds[2 * (b0 + t)], e = bounds[2 * (b0 + t) + 1];
    eflag[t] = (e > s) ? 1.0f : 0.0f;
  }
  __syncthreads();
  int h = t >> 5;
  float bvk = bv[t];
  float acc[4];
  #pragma unroll
  for (int g = 0; g < 4; ++g) acc[g] = 0.f;
  for (int i4 = 0; i4 < 64; ++i4) {
    float aa[4][4];
    #pragma unroll
    for (int g = 0; g < 4; ++g) {
      float4 v = *reinterpret_cast<const float4*>(&Alds[g * 2048 + h * 256 + i4 * 4]);
      aa[g][0] = v.x; aa[g][1] = v.y; aa[g][2] = v.z; aa[g][3] = v.w;
    }
    #pragma unroll
    for (int j = 0; j < 4; ++j) {
      float wvv = Wv[(size_t)(i4 * 4 + j) * 256 + t];
      #pragma unroll
      for (int g = 0; g < 4; ++g) acc[g] = fmaf(aa[g][j], wvv, acc[g]);
    }
  }
  #pragma unroll
  for (int g = 0; g < 4; ++g) attlds[g * 256 + t] = acc[g] + bvk * eflag[g];
  __syncthreads();
  float boj = bo[t];
  float o[4];
  #pragma unroll
  for (int g = 0; g < 4; ++g) o[g] = boj;
  for (int k4 = 0; k4 < 64; ++k4) {
    float aa[4][4];
    #pragma unroll
    for (int g = 0; g < 4; ++g) {
      float4 v = *reinterpret_cast<const float4*>(&attlds[g * 256 + k4 * 4]);
      aa[g][0] = v.x; aa[g][1] = v.y; aa[g][2] = v.z; aa[g][3] = v.w;
    }
    #pragma unroll
    for (int j = 0; j < 4; ++j) {
      float wo = Wo[(size_t)(k4 * 4 + j) * 256 + t];
      #pragma unroll
      for (int g = 0; g < 4; ++g) o[g] = fmaf(aa[g][j], wo, o[g]);
    }
  }
  #pragma unroll
  for (int g = 0; g < 4; ++g) out[(size_t)(b0 + g) * 256 + t] = o[g];
}

extern "C" void kernel_launch(void* const* d_in, const int* in_sizes, int n_in,
                              void* d_out, int out_size, void* d_ws, size_t ws_size,
                              hipStream_t stream) {
  const float* x   = (const float*)d_in[0];
  const int*   bat = (const int*)d_in[1];
  const float* q   = (const float*)d_in[2];
  const float* Wk  = (const float*)d_in[3];
  const float* bk  = (const float*)d_in[4];
  const float* Wv  = (const float*)d_in[5];
  const float* bv  = (const float*)d_in[6];
  const float* Wo  = (const float*)d_in[7];
  const float* bo  = (const float*)d_in[8];
  float* out = (float*)d_out;

  float* ws = (float*)d_ws;
  float* P      = ws;                 // 2048 floats
  float* c      = ws + 2048;          // 8 floats
  int*   bounds = (int*)(ws + 4096);  // 4096 ints
  float* Ag     = ws + 8192;          // 2048*2048 floats

  k_prep<<<8, 256, 0, stream>>>(Wk, bk, q, P, c);
  k_bounds<<<8, 256, 0, stream>>>(bat, bounds);
  k_fused<<<NGRAPH, 256, 0, stream>>>(x, P, c, bounds, Ag);
  k_out<<<NGRAPH / 4, 256, 0, stream>>>(Ag, bounds, Wv, bv, Wo, bo, out);
}